// Round 1
// baseline (638.925 us; speedup 1.0000x reference)
//
#include <hip/hip_runtime.h>
#include <math.h>

#define H 512
#define W 512
#define NC 64            // 4*16 channels collapsed
#define RAD 4
#define TILE 32
#define REG 48           // TILE + 4*RAD (double halo: two box passes)
#define MID 40           // TILE + 2*RAD
#define PSTRIDE 49       // pad to break 32-bank power-of-2 striding
#define NTOT (NC * H * W)

// ---------------- Kernel 1: global sum of |a| + 1e-12 in double ----------------
__global__ __launch_bounds__(256) void sum_abs_kernel(const float* __restrict__ a,
                                                      double* __restrict__ out) {
    int tid = blockIdx.x * blockDim.x + threadIdx.x;
    int stride = gridDim.x * blockDim.x;
    double s = 0.0;
    for (int i = tid; i < NTOT; i += stride)
        s += fabs((double)a[i]) + 1e-12;
    // wave-64 shuffle reduction
    for (int off = 32; off > 0; off >>= 1)
        s += __shfl_down(s, off);
    if ((threadIdx.x & 63) == 0)
        atomicAdd(out, s);
}

// ---------------- Kernel 2: fused guided filter per 32x32 tile ----------------
// Quantity planes: 0:a  1:ax  2:ay  3:a2x2  4:a2xy  5:a2x
__global__ __launch_bounds__(256) void fgf_kernel(const float* __restrict__ Xg,
                                                  const float* __restrict__ Yg,
                                                  const float* __restrict__ Ag,
                                                  const double* __restrict__ Ssum,
                                                  float* __restrict__ outg) {
    __shared__ float P[6][REG][PSTRIDE];   // 14112 floats
    __shared__ float SXc[TILE * TILE];     // 1024 floats  (total 60544 B)

    const int tid = threadIdx.x;
    const int ch  = blockIdx.z;
    const int tr  = blockIdx.y, tc = blockIdx.x;
    const int gr0 = tr * TILE - 2 * RAD;   // region origin (global coords)
    const int gc0 = tc * TILE - 2 * RAD;

    const size_t chOff = (size_t)ch * H * W;
    const float* Xc = Xg + chOff;
    const float* Yc = Yg + chOff;
    const float* Ac = Ag + chOff;
    const float Sf = (float)(*Ssum);

    // ---- Phase 1: load region, zero-pad outside image, form products ----
    for (int idx = tid; idx < REG * REG; idx += 256) {
        int r = idx / REG, c = idx % REG;
        int gr = gr0 + r, gc = gc0 + c;
        float x = 0.f, y = 0.f, a = 0.f;
        if (gr >= 0 && gr < H && gc >= 0 && gc < W) {
            size_t off = (size_t)gr * W + gc;
            x = Xc[off];
            y = Yc[off];
            a = fabsf(Ac[off]) + 1e-12f;
        }
        float ax = a * x, ay = a * y;
        P[0][r][c] = a;
        P[1][r][c] = ax;
        P[2][r][c] = ay;
        P[3][r][c] = ax * ax;
        P[4][r][c] = ax * ay;
        P[5][r][c] = a * ax;
        if (r >= 8 && r < 8 + TILE && c >= 8 && c < 8 + TILE)
            SXc[(r - 8) * TILE + (c - 8)] = x;
    }
    __syncthreads();

    // ---- Phase 2: horizontal 9-box, in-place sliding sum ----
    // out[j] = sum cols j..j+8  (j = 0..39); writing over col j is safe.
    for (int it = tid; it < 6 * REG; it += 256) {
        int q = it / REG, row = it % REG;
        float* p = P[q][row];
        float s = p[0] + p[1] + p[2] + p[3] + p[4] + p[5] + p[6] + p[7] + p[8];
        float left = p[0];
        p[0] = s;
        for (int j = 1; j < MID; ++j) {
            float nl = p[j];
            s += p[j + 8] - left;
            left = nl;
            p[j] = s;
        }
    }
    __syncthreads();

    // ---- Phase 3: vertical 9-box for all 6 planes, compute A,b per mid pixel ----
    float rA[7], rB[7];
#pragma unroll
    for (int k = 0; k < 7; ++k) {
        int idx = tid + k * 256;
        float Aval = 0.f, Bval = 0.f;
        if (idx < MID * MID) {
            int i = idx / MID, j = idx % MID;
            int gr = gr0 + RAD + i, gc = gc0 + RAD + j;
            if (gr >= 0 && gr < H && gc >= 0 && gc < W) {
                float s1 = 0.f, s6 = 0.f, s4 = 0.f, s5 = 0.f, s2 = 0.f, s3 = 0.f;
#pragma unroll
                for (int r = 0; r < 9; ++r) {
                    s1 += P[0][i + r][j];
                    s6 += P[1][i + r][j];
                    s4 += P[2][i + r][j];
                    s5 += P[3][i + r][j];
                    s2 += P[4][i + r][j];
                    s3 += P[5][i + r][j];
                }
                int cy = min(H - 1, gr + RAD) - max(0, gr - RAD) + 1;
                int cx = min(W - 1, gc + RAD) - max(0, gc - RAD) + 1;
                float Nf = (float)(cy * cx);
                float num = s2 - s3 * s4 / Sf;
                float den = fabsf(s5 - s3 * s6 / Sf) + 1e-8f * Nf;
                Aval = num / den;
                Bval = (s4 - Aval * s6) / s1;
            }
        }
        rA[k] = Aval;
        rB[k] = Bval;
    }
    __syncthreads();
#pragma unroll
    for (int k = 0; k < 7; ++k) {
        int idx = tid + k * 256;
        if (idx < MID * MID) {
            int i = idx / MID, j = idx % MID;
            P[0][i][j] = rA[k];   // A on mid grid
            P[1][i][j] = rB[k];   // b on mid grid
        }
    }
    __syncthreads();

    // ---- Phase 4: second horizontal 9-box on A,b (in-place, out cols 0..31) ----
    if (tid < 2 * MID) {
        int q = tid & 1, row = tid >> 1;
        float* p = P[q][row];
        float s = p[0] + p[1] + p[2] + p[3] + p[4] + p[5] + p[6] + p[7] + p[8];
        float left = p[0];
        p[0] = s;
        for (int j = 1; j < TILE; ++j) {
            float nl = p[j];
            s += p[j + 8] - left;
            left = nl;
            p[j] = s;
        }
    }
    __syncthreads();

    // ---- Phase 5: second vertical 9-box + final affine output ----
    for (int idx = tid; idx < TILE * TILE; idx += 256) {
        int row = idx / TILE, col = idx % TILE;
        float sA = 0.f, sB = 0.f;
#pragma unroll
        for (int r = 0; r < 9; ++r) {
            sA += P[0][row + r][col];
            sB += P[1][row + r][col];
        }
        int gr = tr * TILE + row, gc = tc * TILE + col;
        int cy = min(H - 1, gr + RAD) - max(0, gr - RAD) + 1;
        int cx = min(W - 1, gc + RAD) - max(0, gc - RAD) + 1;
        float Nf = (float)(cy * cx);
        float x = SXc[idx];
        outg[chOff + (size_t)gr * W + gc] = (sA / Nf) * x + sB / Nf;
    }
}

extern "C" void kernel_launch(void* const* d_in, const int* in_sizes, int n_in,
                              void* d_out, int out_size, void* d_ws, size_t ws_size,
                              hipStream_t stream) {
    const float* lr_x = (const float*)d_in[0];
    const float* lr_y = (const float*)d_in[1];
    const float* l_a  = (const float*)d_in[2];
    float* out = (float*)d_out;
    double* dsum = (double*)d_ws;

    hipMemsetAsync(d_ws, 0, sizeof(double), stream);
    sum_abs_kernel<<<256, 256, 0, stream>>>(l_a, dsum);

    dim3 grid(W / TILE, H / TILE, NC);
    fgf_kernel<<<grid, 256, 0, stream>>>(lr_x, lr_y, l_a, dsum, out);
}

// Round 2
// 580.994 us; speedup vs baseline: 1.0997x; 1.0997x over previous
//
#include <hip/hip_runtime.h>
#include <math.h>

#define H 512
#define W 512
#define NC 64
#define RAD 4
#define TILE 32
#define REG 48          // TILE + 4*RAD
#define MID 40          // TILE + 2*RAD
#define NQ 12           // quads per region row
#define SLOT 52         // floats per plane slot within a row (>=48, 20 mod 32)
#define ROWST 316       // row stride in floats = 6*SLOT + 4 (28 mod 32)
#define NTOT (NC * H * W)

// ---------------- Kernel 1: global sum of |a| + 1e-12 (fp64) ----------------
__global__ __launch_bounds__(256) void sum_abs_kernel(const float* __restrict__ a,
                                                      double* __restrict__ out) {
    const float4* a4 = (const float4*)a;
    int tid = blockIdx.x * 256 + threadIdx.x;
    int stride = gridDim.x * 256;
    double s = 0.0;
    for (int i = tid; i < NTOT / 4; i += stride) {
        float4 v = a4[i];
        s += (double)fabsf(v.x) + (double)fabsf(v.y) +
             (double)fabsf(v.z) + (double)fabsf(v.w);
    }
    if (blockIdx.x == 0 && threadIdx.x == 0) s += (double)NTOT * 1e-12;
    for (int off = 32; off; off >>= 1) s += __shfl_down(s, off);
    if ((threadIdx.x & 63) == 0) atomicAdd(out, s);
}

// ---------------- Kernel 2: fused guided filter, 32x32 tile ----------------
// Plane slots within each row: 0:a  1:ax  2:ay  3:ax*ax  4:ax*ay  5:a*ax
// After phase 3, slots 0/1 are reused for A/b.
__global__ __launch_bounds__(256) void fgf_kernel(const float* __restrict__ Xg,
                                                  const float* __restrict__ Yg,
                                                  const float* __restrict__ Ag,
                                                  const double* __restrict__ Ssum,
                                                  float* __restrict__ outg) {
    __shared__ float P[REG * ROWST];   // 48*316 floats = 60672 B
    __shared__ float SX[TILE * TILE];  // 4096 B  (total 64768 B)

    const int tid = threadIdx.x;
    const int ch  = blockIdx.z;
    const int tr  = blockIdx.y, tc = blockIdx.x;
    const int gr0 = tr * TILE - 2 * RAD;
    const int gc0 = tc * TILE - 2 * RAD;

    const size_t chOff = (size_t)ch * H * W;
    const float* Xc = Xg + chOff;
    const float* Yc = Yg + chOff;
    const float* Ac = Ag + chOff;
    const float invS = (float)(1.0 / Ssum[0]);

    // ---- Phase 1: float4 load region, form 6 product planes ----
    for (int idx = tid; idx < REG * NQ; idx += 256) {
        int r = idx / NQ, q = idx % NQ;
        int gr = gr0 + r, gc = gc0 + 4 * q;
        float4 x4 = make_float4(0.f, 0.f, 0.f, 0.f);
        float4 y4 = x4, a4 = x4;
        if (gr >= 0 && gr < H && gc >= 0 && gc < W) {
            size_t off = (size_t)gr * W + gc;
            x4 = *(const float4*)(Xc + off);
            y4 = *(const float4*)(Yc + off);
            a4 = *(const float4*)(Ac + off);
            a4.x = fabsf(a4.x) + 1e-12f; a4.y = fabsf(a4.y) + 1e-12f;
            a4.z = fabsf(a4.z) + 1e-12f; a4.w = fabsf(a4.w) + 1e-12f;
        }
        float4 ax = make_float4(a4.x * x4.x, a4.y * x4.y, a4.z * x4.z, a4.w * x4.w);
        float4 ay = make_float4(a4.x * y4.x, a4.y * y4.y, a4.z * y4.z, a4.w * y4.w);
        float* base = &P[r * ROWST + 4 * q];
        *(float4*)(base + 0 * SLOT) = a4;
        *(float4*)(base + 1 * SLOT) = ax;
        *(float4*)(base + 2 * SLOT) = ay;
        *(float4*)(base + 3 * SLOT) = make_float4(ax.x * ax.x, ax.y * ax.y, ax.z * ax.z, ax.w * ax.w);
        *(float4*)(base + 4 * SLOT) = make_float4(ax.x * ay.x, ax.y * ay.y, ax.z * ay.z, ax.w * ay.w);
        *(float4*)(base + 5 * SLOT) = make_float4(a4.x * ax.x, a4.y * ax.y, a4.z * ax.z, a4.w * ax.w);
        if (r >= 8 && r < 8 + TILE && q >= 2 && q < 10)
            *(float4*)&SX[((r - 8) * 8 + (q - 2)) * 4] = x4;
    }
    __syncthreads();

    // ---- Phase 2: vertical 9-box, sliding, thread per (plane, quad-col), in-place ----
    if (tid < 6 * NQ) {
        int p = tid / NQ, qc = tid % NQ;
        float* cb = &P[p * SLOT + 4 * qc];
        float4 w[9];
        float4 s;
#pragma unroll
        for (int k = 0; k < 9; ++k) w[k] = *(float4*)(cb + k * ROWST);
        s.x = w[0].x + w[1].x + w[2].x + w[3].x + w[4].x + w[5].x + w[6].x + w[7].x + w[8].x;
        s.y = w[0].y + w[1].y + w[2].y + w[3].y + w[4].y + w[5].y + w[6].y + w[7].y + w[8].y;
        s.z = w[0].z + w[1].z + w[2].z + w[3].z + w[4].z + w[5].z + w[6].z + w[7].z + w[8].z;
        s.w = w[0].w + w[1].w + w[2].w + w[3].w + w[4].w + w[5].w + w[6].w + w[7].w + w[8].w;
        *(float4*)cb = s;
#pragma unroll
        for (int i = 1; i < MID; ++i) {
            float4 nw = *(float4*)(cb + (i + 8) * ROWST);
            int sl = (i + 8) % 9;
            s.x += nw.x - w[sl].x; s.y += nw.y - w[sl].y;
            s.z += nw.z - w[sl].z; s.w += nw.w - w[sl].w;
            w[sl] = nw;
            *(float4*)(cb + i * ROWST) = s;
        }
    }
    __syncthreads();

    // ---- Phase 3: horizontal 9-box in registers + A/b solve per 4 pixels ----
    float4 rA[2], rB[2];
#pragma unroll
    for (int k = 0; k < 2; ++k) {
        int idx = tid + k * 256;
        float4 Av = make_float4(0.f, 0.f, 0.f, 0.f), Bv = Av;
        if (idx < MID * 10) {
            int i = idx / 10, j0 = (idx % 10) * 4;
            int gr = gr0 + RAD + i;
            int gc = gc0 + RAD + j0;
            if (gr >= 0 && gr < H && gc >= 0 && gc < W) {
                float4 s[6];
#pragma unroll
                for (int p = 0; p < 6; ++p) {
                    const float* c = &P[i * ROWST + p * SLOT + j0];
                    float4 u0 = *(const float4*)c;
                    float4 u1 = *(const float4*)(c + 4);
                    float4 u2 = *(const float4*)(c + 8);
                    float h0 = u0.x + u0.y + u0.z + u0.w + u1.x + u1.y + u1.z + u1.w + u2.x;
                    float h1 = h0 + u2.y - u0.x;
                    float h2 = h1 + u2.z - u0.y;
                    float h3 = h2 + u2.w - u0.z;
                    s[p] = make_float4(h0, h1, h2, h3);
                }
                // s1=s[0] s6=s[1] s4=s[2] s5=s[3] s2=s[4] s3=s[5]
                int cy = min(H - 1, gr + RAD) - max(0, gr - RAD) + 1;
                float fy = (float)cy;
#pragma unroll
                for (int cc = 0; cc < 4; ++cc) {
                    float s1 = ((const float*)&s[0])[cc];
                    float s6 = ((const float*)&s[1])[cc];
                    float s4 = ((const float*)&s[2])[cc];
                    float s5 = ((const float*)&s[3])[cc];
                    float s2 = ((const float*)&s[4])[cc];
                    float s3 = ((const float*)&s[5])[cc];
                    int gcc = gc + cc;
                    int cx = min(W - 1, gcc + RAD) - max(0, gcc - RAD) + 1;
                    float Nf = fy * (float)cx;
                    float num = s2 - s3 * s4 * invS;
                    float den = fabsf(s5 - s3 * s6 * invS) + 1e-8f * Nf;
                    float Aval = num * __builtin_amdgcn_rcpf(den);
                    float Bval = (s4 - Aval * s6) * __builtin_amdgcn_rcpf(s1);
                    ((float*)&Av)[cc] = Aval;
                    ((float*)&Bv)[cc] = Bval;
                }
            }
        }
        rA[k] = Av;
        rB[k] = Bv;
    }
    __syncthreads();
#pragma unroll
    for (int k = 0; k < 2; ++k) {
        int idx = tid + k * 256;
        if (idx < MID * 10) {
            int i = idx / 10, j0 = (idx % 10) * 4;
            *(float4*)&P[i * ROWST + 0 * SLOT + j0] = rA[k];
            *(float4*)&P[i * ROWST + 1 * SLOT + j0] = rB[k];
        }
    }
    __syncthreads();

    // ---- Phase 4: vertical 9-box on A/b, sliding, in-place (20 threads) ----
    if (tid < 20) {
        int sl = tid / 10, qc = tid % 10;
        float* cb = &P[sl * SLOT + 4 * qc];
        float4 w[9];
        float4 s;
#pragma unroll
        for (int k = 0; k < 9; ++k) w[k] = *(float4*)(cb + k * ROWST);
        s.x = w[0].x + w[1].x + w[2].x + w[3].x + w[4].x + w[5].x + w[6].x + w[7].x + w[8].x;
        s.y = w[0].y + w[1].y + w[2].y + w[3].y + w[4].y + w[5].y + w[6].y + w[7].y + w[8].y;
        s.z = w[0].z + w[1].z + w[2].z + w[3].z + w[4].z + w[5].z + w[6].z + w[7].z + w[8].z;
        s.w = w[0].w + w[1].w + w[2].w + w[3].w + w[4].w + w[5].w + w[6].w + w[7].w + w[8].w;
        *(float4*)cb = s;
#pragma unroll
        for (int i = 1; i < TILE; ++i) {
            float4 nw = *(float4*)(cb + (i + 8) * ROWST);
            int slq = (i + 8) % 9;
            s.x += nw.x - w[slq].x; s.y += nw.y - w[slq].y;
            s.z += nw.z - w[slq].z; s.w += nw.w - w[slq].w;
            w[slq] = nw;
            *(float4*)(cb + i * ROWST) = s;
        }
    }
    __syncthreads();

    // ---- Phase 5: horizontal 9-box on A/b + final affine, 1 quad-pixel/thread ----
    {
        int row = tid >> 3, j0 = (tid & 7) * 4;
        const float* cA = &P[row * ROWST + 0 * SLOT + j0];
        const float* cB = &P[row * ROWST + 1 * SLOT + j0];
        float4 a0 = *(const float4*)cA, a1 = *(const float4*)(cA + 4), a2 = *(const float4*)(cA + 8);
        float4 b0 = *(const float4*)cB, b1 = *(const float4*)(cB + 4), b2 = *(const float4*)(cB + 8);
        float hA0 = a0.x + a0.y + a0.z + a0.w + a1.x + a1.y + a1.z + a1.w + a2.x;
        float hA1 = hA0 + a2.y - a0.x;
        float hA2 = hA1 + a2.z - a0.y;
        float hA3 = hA2 + a2.w - a0.z;
        float hB0 = b0.x + b0.y + b0.z + b0.w + b1.x + b1.y + b1.z + b1.w + b2.x;
        float hB1 = hB0 + b2.y - b0.x;
        float hB2 = hB1 + b2.z - b0.y;
        float hB3 = hB2 + b2.w - b0.z;
        float4 xv = *(const float4*)&SX[tid * 4];
        int gr = tr * TILE + row;
        int gcb = tc * TILE + j0;
        int cy = min(H - 1, gr + RAD) - max(0, gr - RAD) + 1;
        float fy = (float)cy;
        float4 o;
        {
            int cx = min(W - 1, gcb + RAD) - max(0, gcb - RAD) + 1;
            o.x = (hA0 * xv.x + hB0) * __builtin_amdgcn_rcpf(fy * (float)cx);
        }
        {
            int cx = min(W - 1, gcb + 1 + RAD) - max(0, gcb + 1 - RAD) + 1;
            o.y = (hA1 * xv.y + hB1) * __builtin_amdgcn_rcpf(fy * (float)cx);
        }
        {
            int cx = min(W - 1, gcb + 2 + RAD) - max(0, gcb + 2 - RAD) + 1;
            o.z = (hA2 * xv.z + hB2) * __builtin_amdgcn_rcpf(fy * (float)cx);
        }
        {
            int cx = min(W - 1, gcb + 3 + RAD) - max(0, gcb + 3 - RAD) + 1;
            o.w = (hA3 * xv.w + hB3) * __builtin_amdgcn_rcpf(fy * (float)cx);
        }
        *(float4*)(outg + chOff + (size_t)gr * W + gcb) = o;
    }
}

extern "C" void kernel_launch(void* const* d_in, const int* in_sizes, int n_in,
                              void* d_out, int out_size, void* d_ws, size_t ws_size,
                              hipStream_t stream) {
    const float* lr_x = (const float*)d_in[0];
    const float* lr_y = (const float*)d_in[1];
    const float* l_a  = (const float*)d_in[2];
    float* out = (float*)d_out;
    double* dsum = (double*)d_ws;

    hipMemsetAsync(d_ws, 0, sizeof(double), stream);
    sum_abs_kernel<<<4096, 256, 0, stream>>>(l_a, dsum);

    dim3 grid(W / TILE, H / TILE, NC);
    fgf_kernel<<<grid, 256, 0, stream>>>(lr_x, lr_y, l_a, dsum, out);
}

// Round 3
// 317.798 us; speedup vs baseline: 2.0105x; 1.8282x over previous
//
#include <hip/hip_runtime.h>
#include <math.h>

#define H 512
#define W 512
#define NC 64
#define NTOT (NC * H * W)
#define RAD 4
#define TILE 32
#define COLLEN 49        // float4 slots per column: 48 rows + 1 pad (49%8=1 -> bank spread)
#define PL (10 * COLLEN) // plane stride in float4

__device__ __forceinline__ float4 f4add(float4 a, float4 b) {
    return make_float4(a.x + b.x, a.y + b.y, a.z + b.z, a.w + b.w);
}
__device__ __forceinline__ float4 f4sub(float4 a, float4 b) {
    return make_float4(a.x - b.x, a.y - b.y, a.z - b.z, a.w - b.w);
}

// h-sum of 9-window over 12 consecutive values -> 4 outputs (cols 4..7 of the 12)
__device__ __forceinline__ float4 hsum9(const float* v) {
    float h0 = v[0] + v[1] + v[2] + v[3] + v[4] + v[5] + v[6] + v[7] + v[8];
    float h1 = h0 - v[0] + v[9];
    float h2 = h1 - v[1] + v[10];
    float h3 = h2 - v[2] + v[11];
    return make_float4(h0, h1, h2, h3);
}

// ---------- sum of |a|+1e-12, atomic-free two-stage ----------
__global__ __launch_bounds__(256) void sum_abs_stage1(const float* __restrict__ a,
                                                      double* __restrict__ ws) {
    __shared__ double red[4];
    const float4* a4 = (const float4*)a;
    int tid = threadIdx.x;
    double s = 0.0;
    for (int i = blockIdx.x * 256 + tid; i < NTOT / 4; i += 1024 * 256) {
        float4 v = a4[i];
        s += (double)fabsf(v.x) + (double)fabsf(v.y) + (double)fabsf(v.z) + (double)fabsf(v.w);
    }
    for (int off = 32; off; off >>= 1) s += __shfl_down(s, off);
    if ((tid & 63) == 0) red[tid >> 6] = s;
    __syncthreads();
    if (tid == 0) ws[1 + blockIdx.x] = red[0] + red[1] + red[2] + red[3];
}

__global__ __launch_bounds__(256) void sum_abs_stage2(double* __restrict__ ws) {
    __shared__ double red[4];
    int tid = threadIdx.x;
    double s = 0.0;
#pragma unroll
    for (int k = 0; k < 4; ++k) s += ws[1 + tid + k * 256];
    for (int off = 32; off; off >>= 1) s += __shfl_down(s, off);
    if ((tid & 63) == 0) red[tid >> 6] = s;
    __syncthreads();
    if (tid == 0) ws[0] = red[0] + red[1] + red[2] + red[3] + (double)NTOT * 1e-12;
}

// ---------- fused guided filter, 32x32 tile ----------
// LDS: 6 planes, column-major float4: P[(plane*10 + mq)*COLLEN + row]
// planes: 0:a 1:ax 2:ay 3:ax^2 4:ax*ay 5:a*ax ; planes 0/1 reused for A/b.
__global__ __launch_bounds__(256) void fgf_kernel(const float* __restrict__ Xg,
                                                  const float* __restrict__ Yg,
                                                  const float* __restrict__ Ag,
                                                  const double* __restrict__ Ssum,
                                                  float* __restrict__ outg) {
    __shared__ float4 P[6 * PL];   // 47040 B -> 3 blocks/CU

    const int tid = threadIdx.x;
    const int ch = blockIdx.z;
    const int tr = blockIdx.y, tc = blockIdx.x;
    const int gr0 = tr * TILE - 8, gc0 = tc * TILE - 8;
    const size_t chOff = (size_t)ch * H * W;
    const float* Xc = Xg + chOff;
    const float* Yc = Yg + chOff;
    const float* Ac = Ag + chOff;
    const float invS = (float)(1.0 / Ssum[0]);

    // ---- Phase 1: load 12-col strip, h-sum 9-window in registers, write 6 planes ----
    for (int idx = tid; idx < 48 * 10; idx += 256) {
        const int i = idx / 10, mq = idx % 10;
        const int gr = gr0 + i;
        const int gcb = gc0 + 4 * mq;
        const bool rok = (gr >= 0) && (gr < H);
        const float* rowx = Xc + (size_t)gr * W;
        const float* rowy = Yc + (size_t)gr * W;
        const float* rowa = Ac + (size_t)gr * W;
        float xr[12], yr[12], ar[12];
#pragma unroll
        for (int k = 0; k < 3; ++k) {
            int gc = gcb + 4 * k;
            float4 xv = make_float4(0.f, 0.f, 0.f, 0.f), yv = xv, av = xv;
            if (rok && gc >= 0 && gc < W) {
                xv = *(const float4*)(rowx + gc);
                yv = *(const float4*)(rowy + gc);
                av = *(const float4*)(rowa + gc);
            }
            xr[4 * k] = xv.x; xr[4 * k + 1] = xv.y; xr[4 * k + 2] = xv.z; xr[4 * k + 3] = xv.w;
            yr[4 * k] = yv.x; yr[4 * k + 1] = yv.y; yr[4 * k + 2] = yv.z; yr[4 * k + 3] = yv.w;
            ar[4 * k] = av.x; ar[4 * k + 1] = av.y; ar[4 * k + 2] = av.z; ar[4 * k + 3] = av.w;
        }
        float a_[12], ax_[12], ay_[12];
#pragma unroll
        for (int j = 0; j < 12; ++j) {
            float aa = fabsf(ar[j]) + 1e-12f;
            a_[j] = aa; ax_[j] = aa * xr[j]; ay_[j] = aa * yr[j];
        }
        float4* base = P + mq * COLLEN + i;
        base[0 * PL] = hsum9(a_);
        base[1 * PL] = hsum9(ax_);
        base[2 * PL] = hsum9(ay_);
        float t[12];
#pragma unroll
        for (int j = 0; j < 12; ++j) t[j] = ax_[j] * ax_[j];
        base[3 * PL] = hsum9(t);
#pragma unroll
        for (int j = 0; j < 12; ++j) t[j] = ax_[j] * ay_[j];
        base[4 * PL] = hsum9(t);
#pragma unroll
        for (int j = 0; j < 12; ++j) t[j] = a_[j] * ax_[j];
        base[5 * PL] = hsum9(t);
    }
    __syncthreads();

    // ---- Phase 2: vertical 9-box, in-place. 240 threads = 6 planes x 10 mq x 4 segs.
    // Whole 18-row input window preloaded to regs BEFORE barrier (halo race -> barrier).
    {
        const int pq2 = tid % 60;
        const int r0 = (tid / 60) * 10;
        float4* col = P + pq2 * COLLEN;
        float4 wv[18];
        if (tid < 240) {
#pragma unroll
            for (int k = 0; k < 18; ++k) wv[k] = col[r0 + k];
        }
        __syncthreads();
        if (tid < 240) {
            float4 s = wv[0];
#pragma unroll
            for (int k = 1; k < 9; ++k) s = f4add(s, wv[k]);
            col[r0] = s;
#pragma unroll
            for (int m = 1; m < 10; ++m) {
                s = f4add(s, f4sub(wv[m + 8], wv[m - 1]));
                col[r0 + m] = s;
            }
        }
        __syncthreads();
    }

    // ---- Phase 3: solve A,b per mid quad (40x40 -> 400 quads), in-place planes 0/1 ----
#pragma unroll
    for (int pass = 0; pass < 2; ++pass) {
        const int idx = tid + pass * 256;
        if (idx < 400) {
            const int mi = idx / 10, mq = idx % 10;
            float4* c0 = P + mq * COLLEN + mi;
            float4 s1 = c0[0 * PL];
            float4 s6 = c0[1 * PL];
            float4 s4 = c0[2 * PL];
            float4 s5 = c0[3 * PL];
            float4 s2 = c0[4 * PL];
            float4 s3 = c0[5 * PL];
            const int gr = gr0 + RAD + mi, gc = gc0 + RAD + 4 * mq;
            float4 A4 = make_float4(0.f, 0.f, 0.f, 0.f), B4 = A4;
            if (gr >= 0 && gr < H && gc >= 0 && gc < W) {
                const float fy = (float)(min(H - 1, gr + RAD) - max(0, gr - RAD) + 1);
#define SOLVE(cc, off)                                                              \
                {                                                                   \
                    float cx = (float)(min(W - 1, gc + off + RAD) - max(0, gc + off - RAD) + 1); \
                    float Nf = fy * cx;                                             \
                    float num = s2.cc - s3.cc * s4.cc * invS;                       \
                    float den = fabsf(s5.cc - s3.cc * s6.cc * invS) + 1e-8f * Nf;   \
                    float Av = num * __builtin_amdgcn_rcpf(den);                    \
                    A4.cc = Av;                                                     \
                    B4.cc = (s4.cc - Av * s6.cc) * __builtin_amdgcn_rcpf(s1.cc);    \
                }
                SOLVE(x, 0) SOLVE(y, 1) SOLVE(z, 2) SOLVE(w, 3)
#undef SOLVE
            }
            c0[0 * PL] = A4;
            c0[1 * PL] = B4;
        }
    }
    __syncthreads();

    // ---- Phase 4: vertical 9-box on A/b, in-place rows 0..31. 160 threads =
    // 8 segs x {A,b} x 10 mq; 12-row window preloaded before barrier.
    {
        const int rem = tid % 20;
        const int pq4 = (rem / 10) * 10 + (rem % 10);   // plane(0/1)*10 + mq
        const int r0 = (tid / 20) * 4;
        float4* col = P + pq4 * COLLEN;
        float4 u[12];
        if (tid < 160) {
#pragma unroll
            for (int k = 0; k < 12; ++k) u[k] = col[r0 + k];
        }
        __syncthreads();
        if (tid < 160) {
            float4 s = u[0];
#pragma unroll
            for (int k = 1; k < 9; ++k) s = f4add(s, u[k]);
            col[r0] = s;
#pragma unroll
            for (int m = 1; m < 4; ++m) {
                s = f4add(s, f4sub(u[m + 8], u[m - 1]));
                col[r0 + m] = s;
            }
        }
        __syncthreads();
    }

    // ---- Phase 5: horizontal 9-box on A/b + final affine; 256 threads, 1 out-quad each ----
    {
        const int orow = tid >> 3, oq = tid & 7;
        const float4* cA = P + oq * COLLEN + orow;
        const float4* cB = cA + 1 * PL;
        float4 a0 = cA[0], a1 = cA[COLLEN], a2 = cA[2 * COLLEN];
        float4 b0 = cB[0], b1 = cB[COLLEN], b2 = cB[2 * COLLEN];
        float hA0 = a0.x + a0.y + a0.z + a0.w + a1.x + a1.y + a1.z + a1.w + a2.x;
        float hA1 = hA0 - a0.x + a2.y;
        float hA2 = hA1 - a0.y + a2.z;
        float hA3 = hA2 - a0.z + a2.w;
        float hB0 = b0.x + b0.y + b0.z + b0.w + b1.x + b1.y + b1.z + b1.w + b2.x;
        float hB1 = hB0 - b0.x + b2.y;
        float hB2 = hB1 - b0.y + b2.z;
        float hB3 = hB2 - b0.z + b2.w;
        const int gr = tr * TILE + orow, gc = tc * TILE + 4 * oq;
        float4 xv = *(const float4*)(Xc + (size_t)gr * W + gc);
        const float fy = (float)(min(H - 1, gr + RAD) - max(0, gr - RAD) + 1);
        float4 o;
#define FIN(cc, hA, hB, off)                                                        \
        {                                                                           \
            float cx = (float)(min(W - 1, gc + off + RAD) - max(0, gc + off - RAD) + 1); \
            o.cc = (hA * xv.cc + hB) * __builtin_amdgcn_rcpf(fy * cx);              \
        }
        FIN(x, hA0, hB0, 0) FIN(y, hA1, hB1, 1) FIN(z, hA2, hB2, 2) FIN(w, hA3, hB3, 3)
#undef FIN
        *(float4*)(outg + chOff + (size_t)gr * W + gc) = o;
    }
}

extern "C" void kernel_launch(void* const* d_in, const int* in_sizes, int n_in,
                              void* d_out, int out_size, void* d_ws, size_t ws_size,
                              hipStream_t stream) {
    const float* lr_x = (const float*)d_in[0];
    const float* lr_y = (const float*)d_in[1];
    const float* l_a  = (const float*)d_in[2];
    float* out = (float*)d_out;
    double* dws = (double*)d_ws;

    sum_abs_stage1<<<1024, 256, 0, stream>>>(l_a, dws);
    sum_abs_stage2<<<1, 256, 0, stream>>>(dws);

    dim3 grid(W / TILE, H / TILE, NC);
    fgf_kernel<<<grid, 256, 0, stream>>>(lr_x, lr_y, l_a, dws, out);
}